// Round 11
// baseline (852.994 us; speedup 1.0000x reference)
//
#include <hip/hip_runtime.h>
#include <stdint.h>

#define N_NODES 100000
#define N_EDGES 1600000
#define HDIM    128
#define G_GRAPHS 64
#define NTOT (N_EDGES + N_NODES)
#define PSLOTS 64
#define NSTRIPS (N_NODES / 16)              // 6250
#define NTB 1024                             // transform blocks in fused kernel
#define NDB ((N_EDGES + 2047) / 2048)        // 782 edge blocks (8 edges/thread)
#define BSH 9                                // bucket = dst >> 9 (512 nodes/bucket)
#define NBK ((N_NODES + 511) / 512)          // 196 buckets
#define MAXBKT 10240                         // rank-LDS cap (mean 8192, +22 sigma)
#define AGRID 2048                           // persistent agg grid (8 blocks/CU)

static_assert(N_NODES % 16 == 0, "tile/agg");
static_assert(N_NODES < (1 << 17), "src fits 17 bits");
static_assert(NBK <= 256, "inline bucket scan single pass");

typedef __attribute__((ext_vector_type(8))) short bf16x8;
typedef __attribute__((ext_vector_type(4))) float f32x4;
typedef __attribute__((ext_vector_type(2))) float f32x2;

__device__ __forceinline__ uint32_t f2bf(float x) {            // RNE f32->bf16
    uint32_t b = __float_as_uint(x);
    return (b + 0x7FFFu + ((b >> 16) & 1u)) >> 16;
}
__device__ __forceinline__ uint32_t pack2(float lo, float hi) {
    return f2bf(lo) | (f2bf(hi) << 16);
}

#define FXSCALE 1099511627776.0f   // 2^40

// ---- swizzle W1,W2,W3 (f32 natural) -> bf16 MFMA B-frag order; zero pp ----
__global__ void k_wswz(const float* __restrict__ Wa, const float* __restrict__ Wb,
                       const float* __restrict__ Wc, uint16_t* __restrict__ dst,
                       float* __restrict__ pp) {
    int gi = blockIdx.x * 256 + threadIdx.x;      // 0..49151
    if (gi < PSLOTS * G_GRAPHS) pp[gi] = 0.f;     // fold pp memset in (16 blocks)
    int w = gi >> 14, idx = gi & 16383;
    const float* src = (w == 0) ? Wa : (w == 1) ? Wb : Wc;
    int k = idx >> 7, n = idx & 127;
    int kc = k >> 5, kq = (k >> 3) & 3, j = k & 7;
    int nt = n >> 4, nl = n & 15;
    dst[w * 16384 + (((kc * 8 + nt) * 64) + kq * 16 + nl) * 8 + j] = (uint16_t)f2bf(src[idx]);
}

__device__ __forceinline__ bf16x8 load_row_f32(const float* p) {
    float4 a = ((const float4*)p)[0];
    float4 b = ((const float4*)p)[1];
    union { uint32_t u[4]; bf16x8 v; } c;
    c.u[0] = pack2(a.x, a.y); c.u[1] = pack2(a.z, a.w);
    c.u[2] = pack2(b.x, b.y); c.u[3] = pack2(b.z, b.w);
    return c.v;
}

// ---- layer-1 transform body (x f32 in, fp8 out), W-frags from global (L1-hot) ----
__device__ __forceinline__ void transform_body_l1(int tb, int nTB, int tid,
                                                  const float* __restrict__ hin,
                                                  const bf16x8* __restrict__ Wfrag,
                                                  uint32_t* __restrict__ t) {
    int lane = tid & 63;
    int quad = lane >> 4;
    int mrow = lane & 15;
    int gwave = tb * 4 + (tid >> 6);
    int nwaves = nTB * 4;
    for (int strip = gwave; strip < NSTRIPS; strip += nwaves) {
        const float* hrow = hin + ((size_t)(strip * 16 + mrow)) * 128 + quad * 8;
        bf16x8 A0 = load_row_f32(hrow);
        bf16x8 A1 = load_row_f32(hrow + 32);
        bf16x8 A2 = load_row_f32(hrow + 64);
        bf16x8 A3 = load_row_f32(hrow + 96);
        f32x4 acc[8];
#pragma unroll
        for (int nt = 0; nt < 8; nt++) {
            f32x4 a = {0.f, 0.f, 0.f, 0.f};
            a = __builtin_amdgcn_mfma_f32_16x16x32_bf16(A0, Wfrag[(0 * 8 + nt) * 64 + lane], a, 0, 0, 0);
            a = __builtin_amdgcn_mfma_f32_16x16x32_bf16(A1, Wfrag[(1 * 8 + nt) * 64 + lane], a, 0, 0, 0);
            a = __builtin_amdgcn_mfma_f32_16x16x32_bf16(A2, Wfrag[(2 * 8 + nt) * 64 + lane], a, 0, 0, 0);
            a = __builtin_amdgcn_mfma_f32_16x16x32_bf16(A3, Wfrag[(3 * 8 + nt) * 64 + lane], a, 0, 0, 0);
            acc[nt] = a;
        }
#pragma unroll
        for (int nt = 0; nt < 8; nt++) {
#pragma unroll
            for (int r = 0; r < 4; r++) {
                float v = acc[nt][r];
                float nb = __shfl_xor(v, 1);
                int s16 = __builtin_amdgcn_cvt_pk_fp8_f32(v, nb, 0, false); // 2x e4m3
                int hi  = __shfl_xor(s16, 2);
                if (!(lane & 3)) {
                    int orow = strip * 16 + quad * 4 + r;
                    int oc = (nt * 16 + mrow) >> 2;   // dword col 0..31
                    t[(size_t)orow * 32 + oc] = (uint32_t)(s16 & 0xffff) | ((uint32_t)hi << 16);
                }
            }
        }
    }
}

// ---- fused: layer-1 transform (MFMA) + coarse bucket count (LDS histogram) ----
__global__ __launch_bounds__(256) void k_tr_count(
        const int* __restrict__ ei, const float* __restrict__ x,
        const bf16x8* __restrict__ Wfrag, uint32_t* __restrict__ t,
        int* __restrict__ partials) {
    __shared__ int hist[NBK];
    int bi = blockIdx.x;
    // interleave 4 transform : 3 count per 7 blocks (1024 T, 782 C, grid 1806)
    int q7 = bi / 7, r7 = bi % 7;
    int tq = q7 * 4 + r7;
    bool isT = (r7 < 4) && (tq < NTB);
    int tid = threadIdx.x;
    if (isT) {
        transform_body_l1(tq, NTB, tid, x, Wfrag, t);
    } else {
        int nTbef = q7 * 4 + (r7 < 4 ? r7 : 4);
        if (nTbef > NTB) nTbef = NTB;
        int db = bi - nTbef;                    // 0..NDB-1
        for (int i = tid; i < NBK; i += 256) hist[i] = 0;
        __syncthreads();
        int e0 = db * 2048 + tid;
#pragma unroll
        for (int k = 0; k < 8; k++) {
            int e = e0 + k * 256;
            if (e < N_EDGES) atomicAdd(&hist[ei[N_EDGES + e] >> BSH], 1);
        }
        __syncthreads();
        for (int i = tid; i < NBK; i += 256) partials[i * NDB + db] = hist[i];
    }
}

// ---- per-bucket scan of the 782 block-partials -> blockBase + totals ----
__global__ void k_bscan(const int* __restrict__ partials, int* __restrict__ blockBase,
                        int* __restrict__ totals) {
    int b = blockIdx.x, tid = threadIdx.x;
    int v[4]; int s = 0;
#pragma unroll
    for (int j = 0; j < 4; j++) {
        int i = tid * 4 + j;
        v[j] = (i < NDB) ? partials[b * NDB + i] : 0;
        s += v[j];
    }
    __shared__ int sm[256];
    sm[tid] = s; __syncthreads();
    for (int off = 1; off < 256; off <<= 1) {
        int u = 0; if (tid >= off) u = sm[tid - off];
        __syncthreads(); sm[tid] += u; __syncthreads();
    }
    int run = sm[tid] - s;                     // exclusive
#pragma unroll
    for (int j = 0; j < 4; j++) {
        int i = tid * 4 + j;
        if (i < NDB) blockBase[b * NDB + i] = run;
        run += v[j];
    }
    if (tid == 255) totals[b] = sm[255];
}

// ---- scatter edges into bucket regions; bucket starts derived inline from
// totals via LDS scan (k_starts folded away); rank via LDS atomics ----
__global__ __launch_bounds__(256) void k_scatter(
        const int* __restrict__ ei, const float* __restrict__ ew,
        const int* __restrict__ blockBase, const int* __restrict__ totals,
        uint2* __restrict__ recs) {
    __shared__ int hist[NBK];
    __shared__ int basesh[NBK];
    __shared__ int sm[256];
    int tid = threadIdx.x, db = blockIdx.x;
    int v = (tid < NBK) ? totals[tid] : 0;
    sm[tid] = v;
    __syncthreads();
    for (int off = 1; off < 256; off <<= 1) {
        int u = 0; if (tid >= off) u = sm[tid - off];
        __syncthreads(); sm[tid] += u; __syncthreads();
    }
    if (tid < NBK) {
        hist[tid] = 0;
        basesh[tid] = (sm[tid] - v) + blockBase[tid * NDB + db];
    }
    __syncthreads();
    int e0 = db * 2048 + tid;
#pragma unroll
    for (int k = 0; k < 8; k++) {
        int e = e0 + k * 256;
        if (e < N_EDGES) {
            int src = ei[e];
            int dst = ei[N_EDGES + e];
            float w = ew[e];
            int bkt = dst >> BSH;
            int r = atomicAdd(&hist[bkt], 1);
            recs[basesh[bkt] + r] =
                make_uint2((uint32_t)src | ((uint32_t)(dst & 511) << 17),
                           __float_as_uint(w));
        }
    }
}

// ---- per-bucket build: bucket start derived inline from totals; cnt/deg
// (LDS packed fixpoint), offs, dinv, CSR with self-loops ----
__global__ __launch_bounds__(256) void k_build(
        const uint2* __restrict__ recs, const int* __restrict__ totals,
        int* __restrict__ cnt, float* __restrict__ dinv, int* __restrict__ offs,
        int2* __restrict__ csr) {
    __shared__ unsigned long long acc[512];   // (count<<48) | fixpoint(deg)
    __shared__ uint16_t rk[MAXBKT];
    __shared__ int loff[512];
    __shared__ int sm[256];
    __shared__ int e0sh;
    int b = blockIdx.x, tid = threadIdx.x;
    int v = (tid < NBK) ? totals[tid] : 0;
    sm[tid] = v;
    for (int i = tid; i < 512; i += 256) acc[i] = 0ULL;
    __syncthreads();
    for (int off = 1; off < 256; off <<= 1) {
        int u = 0; if (tid >= off) u = sm[tid - off];
        __syncthreads(); sm[tid] += u; __syncthreads();
    }
    if (tid == b) e0sh = sm[tid] - v;          // exclusive prefix at b (b < NBK <= 256)
    __syncthreads();
    int e0 = e0sh, ne = totals[b];
    for (int j = tid; j < ne; j += 256) {     // pass 1: rank + packed deg/cnt
        uint2 rc = recs[e0 + j];
        int dl = (rc.x >> 17) & 511;
        float w = __uint_as_float(rc.y);
        unsigned long long pk = (1ULL << 48) | (unsigned long long)(w * FXSCALE);
        unsigned long long old = atomicAdd(&acc[dl], pk);
        rk[j] = (uint16_t)(old >> 48);
    }
    __syncthreads();
    int nb0 = b << BSH;
    int nreal = N_NODES - nb0; if (nreal > 512) nreal = 512;
    int i0 = tid * 2, i1 = tid * 2 + 1;
    int c0 = (i0 < nreal) ? (int)(acc[i0] >> 48) + 1 : 0;   // +1 = self loop
    int c1 = (i1 < nreal) ? (int)(acc[i1] >> 48) + 1 : 0;
    sm[tid] = c0 + c1;
    __syncthreads();
    for (int off = 1; off < 256; off <<= 1) {
        int u = 0; if (tid >= off) u = sm[tid - off];
        __syncthreads(); sm[tid] += u; __syncthreads();
    }
    // global CSR base of bucket = edge-prefix + self-loop-prefix (nb0 nodes before)
    int run = e0 + nb0 + (sm[tid] - (c0 + c1));
    loff[i0] = run;
    loff[i1] = run + c0;
    if (i0 < nreal) {
        unsigned long long pk = acc[i0];
        int c = (int)(pk >> 48);
        float deg = (float)(pk & ((1ULL << 48) - 1)) * (1.0f / FXSCALE);
        cnt[nb0 + i0] = c;
        offs[nb0 + i0] = run;
        dinv[nb0 + i0] = 1.0f / sqrtf(deg + 1.0f);
        csr[run + c] = make_int2(nb0 + i0, __float_as_int(1.0f));  // self, raw w=1
    }
    if (i1 < nreal) {
        unsigned long long pk = acc[i1];
        int c = (int)(pk >> 48);
        float deg = (float)(pk & ((1ULL << 48) - 1)) * (1.0f / FXSCALE);
        cnt[nb0 + i1] = c;
        offs[nb0 + i1] = run + c0;
        dinv[nb0 + i1] = 1.0f / sqrtf(deg + 1.0f);
        csr[run + c0 + c] = make_int2(nb0 + i1, __float_as_int(1.0f));
    }
    __syncthreads();
    for (int j = tid; j < ne; j += 256) {     // pass 2: place edges
        uint2 rc = recs[e0 + j];
        int dl = (rc.x >> 17) & 511;
        int src = rc.x & 0x1ffff;
        csr[loff[dl] + rk[j]] = make_int2(src, (int)rc.y);
    }
}

// ---- apply w' = dinv[src] * w over all CSR entries (dinv[dst] folded later) ----
__global__ void k_norm(int2* __restrict__ csr, const float* __restrict__ dinv) {
    int p = blockIdx.x * 256 + threadIdx.x;
    if (p < NTOT) {
        int2 c = csr[p];
        csr[p].y = __float_as_int(__int_as_float(c.y) * dinv[c.x]);
    }
}

// ---- edge fetch: broadcast (pre-scaled row offset, weight) from CSR-preload
// lanes via ds_bpermute, issue 8 row loads (r3/r6-proven shape) ----
__device__ __forceinline__ void fetch8(const char* __restrict__ tb, int g4, int lq8,
                                       int base, uint32_t osrc, float wsrc,
                                       uint2 (&va)[8], float (&wf)[8]) {
#pragma unroll
    for (int k = 0; k < 8; k++) {
        int o  = __builtin_amdgcn_ds_bpermute(g4 + base + 4 * k, (int)osrc);
        int wb = __builtin_amdgcn_ds_bpermute(g4 + base + 4 * k, __float_as_int(wsrc));
        wf[k] = __uint_as_float((uint32_t)wb);
        va[k] = *(const uint2*)(tb + (uint32_t)(o + lq8));
    }
}

// ---- packed fp8 accumulate: 4 cvt + 4 v_pk_fma per edge-lane ----
__device__ __forceinline__ void acc8(const uint2 (&va)[8], const float (&wf)[8],
                                     f32x2& p0, f32x2& p1, f32x2& p2, f32x2& p3) {
#pragma unroll
    for (int k = 0; k < 8; k++) {
        f32x2 lo0 = __builtin_amdgcn_cvt_pk_f32_fp8((int)va[k].x, false);
        f32x2 hi0 = __builtin_amdgcn_cvt_pk_f32_fp8((int)va[k].x, true);
        f32x2 lo1 = __builtin_amdgcn_cvt_pk_f32_fp8((int)va[k].y, false);
        f32x2 hi1 = __builtin_amdgcn_cvt_pk_f32_fp8((int)va[k].y, true);
        f32x2 wp = { wf[k], wf[k] };
        p0 += wp * lo0; p1 += wp * hi0; p2 += wp * lo1; p3 += wp * hi1;
    }
}

// ---- gather-aggregate for one node (16-lane group), r6 depth-2 ping-pong ----
// w=0 padding (no scalar tail)
__device__ __forceinline__ void aggregate_node(const char* __restrict__ tb,
        const int2* __restrict__ csr, int beg, int num, int ql, int g4, int lq8,
        f32x2& p0, f32x2& p1, f32x2& p2, f32x2& p3) {
    int2 m0 = make_int2(0, 0), m1 = make_int2(0, 0);
    if (ql < num) m0 = csr[beg + ql];
    if (ql + 16 < num) m1 = csr[beg + 16 + ql];
    uint32_t o0 = (uint32_t)m0.x << 7;      // row byte offset
    uint32_t o1 = (uint32_t)m1.x << 7;
    float w0 = __int_as_float(m0.y), w1 = __int_as_float(m1.y);
    bool c1 = num > 8, c2 = num > 16, c3 = num > 24;
    uint2 va[8], vb[8], vc[8], vd[8];
    float wa[8], wb[8], wc[8], wd[8];
    fetch8(tb, g4, lq8, 0, o0, w0, va, wa);
    if (c1) fetch8(tb, g4, lq8, 32, o0, w0, vb, wb);
    acc8(va, wa, p0, p1, p2, p3);
    if (c2) fetch8(tb, g4, lq8, 0, o1, w1, vc, wc);
    if (c1) acc8(vb, wb, p0, p1, p2, p3);
    if (c3) fetch8(tb, g4, lq8, 32, o1, w1, vd, wd);
    if (c2) acc8(vc, wc, p0, p1, p2, p3);
    if (c3) acc8(vd, wd, p0, p1, p2, p3);
    for (int base = 32; base < num; base += 16) {    // rare spill (num>32)
        int2 mm = make_int2(0, 0);
        if (base + ql < num) mm = csr[beg + base + ql];
        uint32_t oo = (uint32_t)mm.x << 7;
        float mws = __int_as_float(mm.y);
        bool h = base + 8 < num;
        fetch8(tb, g4, lq8, 0, oo, mws, va, wa);
        if (h) fetch8(tb, g4, lq8, 32, oo, mws, vb, wb);
        acc8(va, wa, p0, p1, p2, p3);
        if (h) acc8(vb, wb, p0, p1, p2, p3);
    }
}

__device__ __forceinline__ f32x2 relu2(f32x2 p, float dn, f32x2 b) {
    f32x2 r;
    r.x = fmaxf(p.x * dn + b.x, 0.f);
    r.y = fmaxf(p.y * dn + b.y, 0.f);
    return r;
}

// ---- fused aggregate + transform: PERSISTENT + forced 8 waves/EU budget ----
// __launch_bounds__(256, 8) caps VGPR at 64/lane: the r10 loop wanted 88 and
// halved occupancy; this forces rematerialization instead of register hoarding.
__global__ __launch_bounds__(256, 8) void k_agg_tr(
        const uint32_t* __restrict__ tin, const int* __restrict__ offs,
        const int* __restrict__ cnt, const int2* __restrict__ csr,
        const float* __restrict__ dinv, const float* __restrict__ bias,
        const bf16x8* __restrict__ Wfrag, uint32_t* __restrict__ tout) {
    __shared__ uint32_t ht[16 * 16 * 4];     // [m][slot][4 dwords] = 4 KB
    int tid = threadIdx.x;
    int lane = tid & 63;
    int ql = lane & 15;
    int grp = lane & 48;
    int g4 = grp << 2, lq8 = ql << 3;
    int row = (tid >> 6) * 4 + (lane >> 4);  // local node 0..15
    int quad = lane >> 4;
    int m = lane & 15;
    int wid = tid >> 6;
    for (int strip = blockIdx.x; strip < NSTRIPS; strip += AGRID) {
        int node = strip * 16 + row;
        int beg = offs[node];
        int num = cnt[node] + 1;
        float dn = dinv[node];
        f32x2 p0 = {0.f, 0.f}, p1 = {0.f, 0.f}, p2 = {0.f, 0.f}, p3 = {0.f, 0.f};
        aggregate_node((const char*)tin, csr, beg, num, ql, g4, lq8, p0, p1, p2, p3);
        const f32x2* bp = (const f32x2*)bias;
        p0 = relu2(p0, dn, bp[ql * 4 + 0]);
        p1 = relu2(p1, dn, bp[ql * 4 + 1]);
        p2 = relu2(p2, dn, bp[ql * 4 + 2]);
        p3 = relu2(p3, dn, bp[ql * 4 + 3]);
        {
            int slot = (ql + row) & 15;              // rotate to spread LDS banks
            uint32_t* dst = &ht[(row * 16 + slot) * 4];
            dst[0] = pack2(p0.x, p0.y);
            dst[1] = pack2(p1.x, p1.y);
            dst[2] = pack2(p2.x, p2.y);
            dst[3] = pack2(p3.x, p3.y);
        }
        __syncthreads();
        // ---- transform phase: wave w handles nt = 2w, 2w+1 ----
        bf16x8 A[4];
#pragma unroll
        for (int c = 0; c < 4; c++) {
            int sl = (c * 4 + quad + m) & 15;
            A[c] = *(const bf16x8*)&ht[(m * 16 + sl) * 4];
        }
        __syncthreads();                     // ht consumed; next strip may overwrite
#pragma unroll
        for (int u = 0; u < 2; u++) {
            int nt = wid * 2 + u;
            f32x4 a = {0.f, 0.f, 0.f, 0.f};
            a = __builtin_amdgcn_mfma_f32_16x16x32_bf16(A[0], Wfrag[(0 * 8 + nt) * 64 + lane], a, 0, 0, 0);
            a = __builtin_amdgcn_mfma_f32_16x16x32_bf16(A[1], Wfrag[(1 * 8 + nt) * 64 + lane], a, 0, 0, 0);
            a = __builtin_amdgcn_mfma_f32_16x16x32_bf16(A[2], Wfrag[(2 * 8 + nt) * 64 + lane], a, 0, 0, 0);
            a = __builtin_amdgcn_mfma_f32_16x16x32_bf16(A[3], Wfrag[(3 * 8 + nt) * 64 + lane], a, 0, 0, 0);
#pragma unroll
            for (int r = 0; r < 4; r++) {
                float v = a[r];
                float nb = __shfl_xor(v, 1);
                int s16 = __builtin_amdgcn_cvt_pk_fp8_f32(v, nb, 0, false);
                int hi  = __shfl_xor(s16, 2);
                if (!(lane & 3)) {
                    int orow = strip * 16 + quad * 4 + r;
                    int oc = (nt * 16 + m) >> 2;
                    tout[(size_t)orow * 32 + oc] = (uint32_t)(s16 & 0xffff) | ((uint32_t)hi << 16);
                }
            }
        }
    }
}

// ---- last layer: aggregation + fused pool (persistent, forced budget) ----
__global__ __launch_bounds__(256, 8) void k_agg_pool(
        const uint32_t* __restrict__ t, const int* __restrict__ offs,
        const int* __restrict__ cnt, const int2* __restrict__ csr,
        const float* __restrict__ dinv, const float* __restrict__ bias,
        const float* __restrict__ lw, const int* __restrict__ batch,
        float* __restrict__ pp) {
    int tid = threadIdx.x;
    int lane = tid & 63;
    int ql = lane & 15;
    int grp = lane & 48;
    int g4 = grp << 2, lq8 = ql << 3;
    int row = (tid >> 6) * 4 + (lane >> 4);
    for (int strip = blockIdx.x; strip < NSTRIPS; strip += AGRID) {
        int node = strip * 16 + row;
        int beg = offs[node];
        int num = cnt[node] + 1;
        float dn = dinv[node];
        f32x2 p0 = {0.f, 0.f}, p1 = {0.f, 0.f}, p2 = {0.f, 0.f}, p3 = {0.f, 0.f};
        aggregate_node((const char*)t, csr, beg, num, ql, g4, lq8, p0, p1, p2, p3);
        const f32x2* bp = (const f32x2*)bias;
        p0 = relu2(p0, dn, bp[ql * 4 + 0]);
        p1 = relu2(p1, dn, bp[ql * 4 + 1]);
        p2 = relu2(p2, dn, bp[ql * 4 + 2]);
        p3 = relu2(p3, dn, bp[ql * 4 + 3]);
        const f32x2* wp2 = (const f32x2*)lw;
        f32x2 q0 = wp2[ql * 4 + 0], q1 = wp2[ql * 4 + 1];
        f32x2 q2 = wp2[ql * 4 + 2], q3 = wp2[ql * 4 + 3];
        float d = p0.x * q0.x + p0.y * q0.y + p1.x * q1.x + p1.y * q1.y
                + p2.x * q2.x + p2.y * q2.y + p3.x * q3.x + p3.y * q3.y;
        for (int off = 8; off; off >>= 1) d += __shfl_down(d, off);
        if (ql == 0)
            atomicAdd(&pp[(strip & (PSLOTS - 1)) * G_GRAPHS + batch[node]], d);
    }
}

// ---- final: out[g] = (sum over slots)/cnt_g + lb ----
__global__ void k_final(const float* __restrict__ pp, const int* __restrict__ batch,
                        const float* __restrict__ lb, float* __restrict__ out) {
    int g = threadIdx.x;   // 64 threads
    float s = 0.f;
#pragma unroll
    for (int k = 0; k < PSLOTS; k++) s += pp[k * G_GRAPHS + g];
    int lo = 0, hi = N_NODES;
    while (lo < hi) { int m = (lo + hi) >> 1; if (batch[m] < g) lo = m + 1; else hi = m; }
    int beg = lo;
    hi = N_NODES;
    while (lo < hi) { int m = (lo + hi) >> 1; if (batch[m] < g + 1) lo = m + 1; else hi = m; }
    float c = fmaxf((float)(lo - beg), 1.0f);
    out[g] = s / c + lb[0];
}

extern "C" void kernel_launch(void* const* d_in, const int* in_sizes, int n_in,
                              void* d_out, int out_size, void* d_ws, size_t ws_size,
                              hipStream_t stream) {
    const float* x   = (const float*)d_in[0];
    const float* ew  = (const float*)d_in[1];
    const int*   ei  = (const int*)d_in[2];
    const int*   bat = (const int*)d_in[3];
    const float* W1  = (const float*)d_in[4];
    const float* b1  = (const float*)d_in[5];
    const float* W2  = (const float*)d_in[6];
    const float* b2  = (const float*)d_in[7];
    const float* W3  = (const float*)d_in[8];
    const float* b3  = (const float*)d_in[9];
    const float* lw  = (const float*)d_in[10];
    const float* lb  = (const float*)d_in[11];
    float* out = (float*)d_out;

    char* w = (char*)d_ws;
    size_t o = 0;
    auto carve = [&](size_t bytes) -> void* {
        void* p = w + o;
        o = (o + bytes + 255) & ~(size_t)255;
        return p;
    };
    float*    pp     = (float*)carve((size_t)PSLOTS * G_GRAPHS * 4);
    int*      parts  = (int*)  carve((size_t)NBK * NDB * 4);
    int*      bbase  = (int*)  carve((size_t)NBK * NDB * 4);
    int*      totals = (int*)  carve((size_t)NBK * 4);
    uint2*    recs   = (uint2*)carve((size_t)N_EDGES * 8);
    int*      cnt    = (int*)  carve((size_t)N_NODES * 4);
    float*    dinv   = (float*)carve((size_t)N_NODES * 4);
    int*      offs   = (int*)  carve((size_t)N_NODES * 4);
    int2*     csr    = (int2*) carve((size_t)NTOT * 8);
    uint32_t* tA     = (uint32_t*)carve((size_t)N_NODES * 128);   // fp8 rows
    uint32_t* tB     = (uint32_t*)carve((size_t)N_NODES * 128);   // fp8 rows
    uint16_t* wsz    = (uint16_t*)carve((size_t)3 * 16384 * 2);   // frag-order W1,W2,W3
    (void)ws_size; (void)in_sizes; (void)n_in; (void)out_size;

    // k_wswz also zeroes pp (first 16 blocks) — no separate memset dispatch
    k_wswz<<<192, 256, 0, stream>>>(W1, W2, W3, wsz, pp);
    // fused: layer-1 transform (MFMA, global W-frags) + LDS bucket histogram
    k_tr_count<<<NTB + NDB, 256, 0, stream>>>(ei, x, (const bf16x8*)wsz, tA, parts);
    k_bscan<<<NBK, 256, 0, stream>>>(parts, bbase, totals);
    // bucket starts computed inline in k_scatter/k_build (k_starts folded away)
    k_scatter<<<NDB, 256, 0, stream>>>(ei, ew, bbase, totals, recs);
    k_build<<<NBK, 256, 0, stream>>>(recs, totals, cnt, dinv, offs, csr);
    k_norm<<<(NTOT + 255) / 256, 256, 0, stream>>>(csr, dinv);

    // fused aggregate+transform per layer boundary (h never leaves LDS)
    k_agg_tr<<<AGRID, 256, 0, stream>>>(tA, offs, cnt, csr, dinv, b1,
                                        (const bf16x8*)(wsz + 16384), tB);
    k_agg_tr<<<AGRID, 256, 0, stream>>>(tB, offs, cnt, csr, dinv, b2,
                                        (const bf16x8*)(wsz + 2 * 16384), tA);
    k_agg_pool<<<AGRID, 256, 0, stream>>>(tA, offs, cnt, csr, dinv, b3, lw, bat, pp);

    k_final<<<1, G_GRAPHS, 0, stream>>>(pp, bat, lb, out);
}

// Round 12
// 330.450 us; speedup vs baseline: 2.5813x; 2.5813x over previous
//
#include <hip/hip_runtime.h>
#include <stdint.h>

#define N_NODES 100000
#define N_EDGES 1600000
#define HDIM    128
#define G_GRAPHS 64
#define NTOT (N_EDGES + N_NODES)
#define PSLOTS 64
#define NSTRIPS (N_NODES / 16)              // 6250
#define NTB 1024                             // transform blocks in fused kernel
#define NDB ((N_EDGES + 2047) / 2048)        // 782 edge blocks (8 edges/thread)
#define BSH 9                                // bucket = dst >> 9 (512 nodes/bucket)
#define NBK ((N_NODES + 511) / 512)          // 196 buckets
#define MAXBKT 10240                         // rank-LDS cap (mean 8192, +22 sigma)

static_assert(N_NODES % 16 == 0, "tile/agg");
static_assert(N_NODES < (1 << 17), "src fits 17 bits");
static_assert(NBK <= 256, "inline bucket scan single pass");

typedef __attribute__((ext_vector_type(8))) short bf16x8;
typedef __attribute__((ext_vector_type(4))) float f32x4;
typedef __attribute__((ext_vector_type(2))) float f32x2;

__device__ __forceinline__ uint32_t f2bf(float x) {            // RNE f32->bf16
    uint32_t b = __float_as_uint(x);
    return (b + 0x7FFFu + ((b >> 16) & 1u)) >> 16;
}
__device__ __forceinline__ uint32_t pack2(float lo, float hi) {
    return f2bf(lo) | (f2bf(hi) << 16);
}

#define FXSCALE 1099511627776.0f   // 2^40

// ---- swizzle W1,W2,W3 (f32 natural) -> bf16 MFMA B-frag order; zero pp ----
__global__ void k_wswz(const float* __restrict__ Wa, const float* __restrict__ Wb,
                       const float* __restrict__ Wc, uint16_t* __restrict__ dst,
                       float* __restrict__ pp) {
    int gi = blockIdx.x * 256 + threadIdx.x;      // 0..49151
    if (gi < PSLOTS * G_GRAPHS) pp[gi] = 0.f;     // fold pp memset in (16 blocks)
    int w = gi >> 14, idx = gi & 16383;
    const float* src = (w == 0) ? Wa : (w == 1) ? Wb : Wc;
    int k = idx >> 7, n = idx & 127;
    int kc = k >> 5, kq = (k >> 3) & 3, j = k & 7;
    int nt = n >> 4, nl = n & 15;
    dst[w * 16384 + (((kc * 8 + nt) * 64) + kq * 16 + nl) * 8 + j] = (uint16_t)f2bf(src[idx]);
}

__device__ __forceinline__ bf16x8 load_row_f32(const float* p) {
    float4 a = ((const float4*)p)[0];
    float4 b = ((const float4*)p)[1];
    union { uint32_t u[4]; bf16x8 v; } c;
    c.u[0] = pack2(a.x, a.y); c.u[1] = pack2(a.z, a.w);
    c.u[2] = pack2(b.x, b.y); c.u[3] = pack2(b.z, b.w);
    return c.v;
}

// ---- layer-1 transform body (x f32 in, fp8 out), W-frags from global (L1-hot) ----
__device__ __forceinline__ void transform_body_l1(int tb, int nTB, int tid,
                                                  const float* __restrict__ hin,
                                                  const bf16x8* __restrict__ Wfrag,
                                                  uint32_t* __restrict__ t) {
    int lane = tid & 63;
    int quad = lane >> 4;
    int mrow = lane & 15;
    int gwave = tb * 4 + (tid >> 6);
    int nwaves = nTB * 4;
    for (int strip = gwave; strip < NSTRIPS; strip += nwaves) {
        const float* hrow = hin + ((size_t)(strip * 16 + mrow)) * 128 + quad * 8;
        bf16x8 A0 = load_row_f32(hrow);
        bf16x8 A1 = load_row_f32(hrow + 32);
        bf16x8 A2 = load_row_f32(hrow + 64);
        bf16x8 A3 = load_row_f32(hrow + 96);
        f32x4 acc[8];
#pragma unroll
        for (int nt = 0; nt < 8; nt++) {
            f32x4 a = {0.f, 0.f, 0.f, 0.f};
            a = __builtin_amdgcn_mfma_f32_16x16x32_bf16(A0, Wfrag[(0 * 8 + nt) * 64 + lane], a, 0, 0, 0);
            a = __builtin_amdgcn_mfma_f32_16x16x32_bf16(A1, Wfrag[(1 * 8 + nt) * 64 + lane], a, 0, 0, 0);
            a = __builtin_amdgcn_mfma_f32_16x16x32_bf16(A2, Wfrag[(2 * 8 + nt) * 64 + lane], a, 0, 0, 0);
            a = __builtin_amdgcn_mfma_f32_16x16x32_bf16(A3, Wfrag[(3 * 8 + nt) * 64 + lane], a, 0, 0, 0);
            acc[nt] = a;
        }
#pragma unroll
        for (int nt = 0; nt < 8; nt++) {
#pragma unroll
            for (int r = 0; r < 4; r++) {
                float v = acc[nt][r];
                float nb = __shfl_xor(v, 1);
                int s16 = __builtin_amdgcn_cvt_pk_fp8_f32(v, nb, 0, false); // 2x e4m3
                int hi  = __shfl_xor(s16, 2);
                if (!(lane & 3)) {
                    int orow = strip * 16 + quad * 4 + r;
                    int oc = (nt * 16 + mrow) >> 2;   // dword col 0..31
                    t[(size_t)orow * 32 + oc] = (uint32_t)(s16 & 0xffff) | ((uint32_t)hi << 16);
                }
            }
        }
    }
}

// ---- fused: layer-1 transform (MFMA) + coarse bucket count (LDS histogram) ----
__global__ __launch_bounds__(256) void k_tr_count(
        const int* __restrict__ ei, const float* __restrict__ x,
        const bf16x8* __restrict__ Wfrag, uint32_t* __restrict__ t,
        int* __restrict__ partials) {
    __shared__ int hist[NBK];
    int bi = blockIdx.x;
    // interleave 4 transform : 3 count per 7 blocks (1024 T, 782 C, grid 1806)
    int q7 = bi / 7, r7 = bi % 7;
    int tq = q7 * 4 + r7;
    bool isT = (r7 < 4) && (tq < NTB);
    int tid = threadIdx.x;
    if (isT) {
        transform_body_l1(tq, NTB, tid, x, Wfrag, t);
    } else {
        int nTbef = q7 * 4 + (r7 < 4 ? r7 : 4);
        if (nTbef > NTB) nTbef = NTB;
        int db = bi - nTbef;                    // 0..NDB-1
        for (int i = tid; i < NBK; i += 256) hist[i] = 0;
        __syncthreads();
        int e0 = db * 2048 + tid;
#pragma unroll
        for (int k = 0; k < 8; k++) {
            int e = e0 + k * 256;
            if (e < N_EDGES) atomicAdd(&hist[ei[N_EDGES + e] >> BSH], 1);
        }
        __syncthreads();
        for (int i = tid; i < NBK; i += 256) partials[i * NDB + db] = hist[i];
    }
}

// ---- per-bucket scan of the 782 block-partials -> blockBase + totals ----
__global__ void k_bscan(const int* __restrict__ partials, int* __restrict__ blockBase,
                        int* __restrict__ totals) {
    int b = blockIdx.x, tid = threadIdx.x;
    int v[4]; int s = 0;
#pragma unroll
    for (int j = 0; j < 4; j++) {
        int i = tid * 4 + j;
        v[j] = (i < NDB) ? partials[b * NDB + i] : 0;
        s += v[j];
    }
    __shared__ int sm[256];
    sm[tid] = s; __syncthreads();
    for (int off = 1; off < 256; off <<= 1) {
        int u = 0; if (tid >= off) u = sm[tid - off];
        __syncthreads(); sm[tid] += u; __syncthreads();
    }
    int run = sm[tid] - s;                     // exclusive
#pragma unroll
    for (int j = 0; j < 4; j++) {
        int i = tid * 4 + j;
        if (i < NDB) blockBase[b * NDB + i] = run;
        run += v[j];
    }
    if (tid == 255) totals[b] = sm[255];
}

// ---- scatter edges into bucket regions; bucket starts derived inline from
// totals via LDS scan (k_starts folded away); rank via LDS atomics ----
__global__ __launch_bounds__(256) void k_scatter(
        const int* __restrict__ ei, const float* __restrict__ ew,
        const int* __restrict__ blockBase, const int* __restrict__ totals,
        uint2* __restrict__ recs) {
    __shared__ int hist[NBK];
    __shared__ int basesh[NBK];
    __shared__ int sm[256];
    int tid = threadIdx.x, db = blockIdx.x;
    int v = (tid < NBK) ? totals[tid] : 0;
    sm[tid] = v;
    __syncthreads();
    for (int off = 1; off < 256; off <<= 1) {
        int u = 0; if (tid >= off) u = sm[tid - off];
        __syncthreads(); sm[tid] += u; __syncthreads();
    }
    if (tid < NBK) {
        hist[tid] = 0;
        basesh[tid] = (sm[tid] - v) + blockBase[tid * NDB + db];
    }
    __syncthreads();
    int e0 = db * 2048 + tid;
#pragma unroll
    for (int k = 0; k < 8; k++) {
        int e = e0 + k * 256;
        if (e < N_EDGES) {
            int src = ei[e];
            int dst = ei[N_EDGES + e];
            float w = ew[e];
            int bkt = dst >> BSH;
            int r = atomicAdd(&hist[bkt], 1);
            recs[basesh[bkt] + r] =
                make_uint2((uint32_t)src | ((uint32_t)(dst & 511) << 17),
                           __float_as_uint(w));
        }
    }
}

// ---- per-bucket build: bucket start derived inline from totals; cnt/deg
// (LDS packed fixpoint), offs, dinv, CSR with self-loops ----
__global__ __launch_bounds__(256) void k_build(
        const uint2* __restrict__ recs, const int* __restrict__ totals,
        int* __restrict__ cnt, float* __restrict__ dinv, int* __restrict__ offs,
        int2* __restrict__ csr) {
    __shared__ unsigned long long acc[512];   // (count<<48) | fixpoint(deg)
    __shared__ uint16_t rk[MAXBKT];
    __shared__ int loff[512];
    __shared__ int sm[256];
    __shared__ int e0sh;
    int b = blockIdx.x, tid = threadIdx.x;
    int v = (tid < NBK) ? totals[tid] : 0;
    sm[tid] = v;
    for (int i = tid; i < 512; i += 256) acc[i] = 0ULL;
    __syncthreads();
    for (int off = 1; off < 256; off <<= 1) {
        int u = 0; if (tid >= off) u = sm[tid - off];
        __syncthreads(); sm[tid] += u; __syncthreads();
    }
    if (tid == b) e0sh = sm[tid] - v;          // exclusive prefix at b (b < NBK <= 256)
    __syncthreads();
    int e0 = e0sh, ne = totals[b];
    for (int j = tid; j < ne; j += 256) {     // pass 1: rank + packed deg/cnt
        uint2 rc = recs[e0 + j];
        int dl = (rc.x >> 17) & 511;
        float w = __uint_as_float(rc.y);
        unsigned long long pk = (1ULL << 48) | (unsigned long long)(w * FXSCALE);
        unsigned long long old = atomicAdd(&acc[dl], pk);
        rk[j] = (uint16_t)(old >> 48);
    }
    __syncthreads();
    int nb0 = b << BSH;
    int nreal = N_NODES - nb0; if (nreal > 512) nreal = 512;
    int i0 = tid * 2, i1 = tid * 2 + 1;
    int c0 = (i0 < nreal) ? (int)(acc[i0] >> 48) + 1 : 0;   // +1 = self loop
    int c1 = (i1 < nreal) ? (int)(acc[i1] >> 48) + 1 : 0;
    sm[tid] = c0 + c1;
    __syncthreads();
    for (int off = 1; off < 256; off <<= 1) {
        int u = 0; if (tid >= off) u = sm[tid - off];
        __syncthreads(); sm[tid] += u; __syncthreads();
    }
    // global CSR base of bucket = edge-prefix + self-loop-prefix (nb0 nodes before)
    int run = e0 + nb0 + (sm[tid] - (c0 + c1));
    loff[i0] = run;
    loff[i1] = run + c0;
    if (i0 < nreal) {
        unsigned long long pk = acc[i0];
        int c = (int)(pk >> 48);
        float deg = (float)(pk & ((1ULL << 48) - 1)) * (1.0f / FXSCALE);
        cnt[nb0 + i0] = c;
        offs[nb0 + i0] = run;
        dinv[nb0 + i0] = 1.0f / sqrtf(deg + 1.0f);
        csr[run + c] = make_int2(nb0 + i0, __float_as_int(1.0f));  // self, raw w=1
    }
    if (i1 < nreal) {
        unsigned long long pk = acc[i1];
        int c = (int)(pk >> 48);
        float deg = (float)(pk & ((1ULL << 48) - 1)) * (1.0f / FXSCALE);
        cnt[nb0 + i1] = c;
        offs[nb0 + i1] = run + c0;
        dinv[nb0 + i1] = 1.0f / sqrtf(deg + 1.0f);
        csr[run + c0 + c] = make_int2(nb0 + i1, __float_as_int(1.0f));
    }
    __syncthreads();
    for (int j = tid; j < ne; j += 256) {     // pass 2: place edges
        uint2 rc = recs[e0 + j];
        int dl = (rc.x >> 17) & 511;
        int src = rc.x & 0x1ffff;
        csr[loff[dl] + rk[j]] = make_int2(src, (int)rc.y);
    }
}

// ---- apply w' = dinv[src] * w over all CSR entries (dinv[dst] folded later) ----
__global__ void k_norm(int2* __restrict__ csr, const float* __restrict__ dinv) {
    int p = blockIdx.x * 256 + threadIdx.x;
    if (p < NTOT) {
        int2 c = csr[p];
        csr[p].y = __float_as_int(__int_as_float(c.y) * dinv[c.x]);
    }
}

// ---- edge fetch: broadcast (pre-scaled row offset, weight) from CSR-preload
// lanes via ds_bpermute, issue 8 row loads (r3/r6/r9-proven shape) ----
__device__ __forceinline__ void fetch8(const char* __restrict__ tb, int g4, int lq8,
                                       int base, uint32_t osrc, float wsrc,
                                       uint2 (&va)[8], float (&wf)[8]) {
#pragma unroll
    for (int k = 0; k < 8; k++) {
        int o  = __builtin_amdgcn_ds_bpermute(g4 + base + 4 * k, (int)osrc);
        int wb = __builtin_amdgcn_ds_bpermute(g4 + base + 4 * k, __float_as_int(wsrc));
        wf[k] = __uint_as_float((uint32_t)wb);
        va[k] = *(const uint2*)(tb + (uint32_t)(o + lq8));
    }
}

// ---- packed fp8 accumulate: 4 cvt + 4 v_pk_fma per edge-lane ----
__device__ __forceinline__ void acc8(const uint2 (&va)[8], const float (&wf)[8],
                                     f32x2& p0, f32x2& p1, f32x2& p2, f32x2& p3) {
#pragma unroll
    for (int k = 0; k < 8; k++) {
        f32x2 lo0 = __builtin_amdgcn_cvt_pk_f32_fp8((int)va[k].x, false);
        f32x2 hi0 = __builtin_amdgcn_cvt_pk_f32_fp8((int)va[k].x, true);
        f32x2 lo1 = __builtin_amdgcn_cvt_pk_f32_fp8((int)va[k].y, false);
        f32x2 hi1 = __builtin_amdgcn_cvt_pk_f32_fp8((int)va[k].y, true);
        f32x2 wp = { wf[k], wf[k] };
        p0 += wp * lo0; p1 += wp * hi0; p2 += wp * lo1; p3 += wp * hi1;
    }
}

// ---- gather-aggregate for one node (16-lane group), depth-2 ping-pong ----
// w=0 padding (no scalar tail). Settled optimum: deeper prefetch (r4),
// uniform loads (r5), strip pipeline (r7), imm swizzle (r8), persistence
// (r10), forced occupancy (r11) all measured worse.
__device__ __forceinline__ void aggregate_node(const char* __restrict__ tb,
        const int2* __restrict__ csr, int beg, int num, int ql, int g4, int lq8,
        f32x2& p0, f32x2& p1, f32x2& p2, f32x2& p3) {
    int2 m0 = make_int2(0, 0), m1 = make_int2(0, 0);
    if (ql < num) m0 = csr[beg + ql];
    if (ql + 16 < num) m1 = csr[beg + 16 + ql];
    uint32_t o0 = (uint32_t)m0.x << 7;      // row byte offset
    uint32_t o1 = (uint32_t)m1.x << 7;
    float w0 = __int_as_float(m0.y), w1 = __int_as_float(m1.y);
    bool c1 = num > 8, c2 = num > 16, c3 = num > 24;
    uint2 va[8], vb[8], vc[8], vd[8];
    float wa[8], wb[8], wc[8], wd[8];
    fetch8(tb, g4, lq8, 0, o0, w0, va, wa);
    if (c1) fetch8(tb, g4, lq8, 32, o0, w0, vb, wb);
    acc8(va, wa, p0, p1, p2, p3);
    if (c2) fetch8(tb, g4, lq8, 0, o1, w1, vc, wc);
    if (c1) acc8(vb, wb, p0, p1, p2, p3);
    if (c3) fetch8(tb, g4, lq8, 32, o1, w1, vd, wd);
    if (c2) acc8(vc, wc, p0, p1, p2, p3);
    if (c3) acc8(vd, wd, p0, p1, p2, p3);
    for (int base = 32; base < num; base += 16) {    // rare spill (num>32)
        int2 mm = make_int2(0, 0);
        if (base + ql < num) mm = csr[beg + base + ql];
        uint32_t oo = (uint32_t)mm.x << 7;
        float mws = __int_as_float(mm.y);
        bool h = base + 8 < num;
        fetch8(tb, g4, lq8, 0, oo, mws, va, wa);
        if (h) fetch8(tb, g4, lq8, 32, oo, mws, vb, wb);
        acc8(va, wa, p0, p1, p2, p3);
        if (h) acc8(vb, wb, p0, p1, p2, p3);
    }
}

__device__ __forceinline__ f32x2 relu2(f32x2 p, float dn, f32x2 b) {
    f32x2 r;
    r.x = fmaxf(p.x * dn + b.x, 0.f);
    r.y = fmaxf(p.y * dn + b.y, 0.f);
    return r;
}

// ---- fused aggregate + transform: one block = 16 nodes = one MFMA strip ----
__global__ __launch_bounds__(256) void k_agg_tr(
        const uint32_t* __restrict__ tin, const int* __restrict__ offs,
        const int* __restrict__ cnt, const int2* __restrict__ csr,
        const float* __restrict__ dinv, const float* __restrict__ bias,
        const bf16x8* __restrict__ Wfrag, uint32_t* __restrict__ tout) {
    __shared__ uint32_t ht[16 * 16 * 4];     // [m][slot][4 dwords] = 4 KB
    int tid = threadIdx.x;
    int lane = tid & 63;
    int ql = lane & 15;
    int grp = lane & 48;
    int g4 = grp << 2, lq8 = ql << 3;
    int row = (tid >> 6) * 4 + (lane >> 4);  // local node 0..15
    int node = blockIdx.x * 16 + row;
    int beg = offs[node];
    int num = cnt[node] + 1;
    float dn = dinv[node];
    f32x2 p0 = {0.f, 0.f}, p1 = {0.f, 0.f}, p2 = {0.f, 0.f}, p3 = {0.f, 0.f};
    aggregate_node((const char*)tin, csr, beg, num, ql, g4, lq8, p0, p1, p2, p3);
    const f32x2* bp = (const f32x2*)bias;
    p0 = relu2(p0, dn, bp[ql * 4 + 0]);
    p1 = relu2(p1, dn, bp[ql * 4 + 1]);
    p2 = relu2(p2, dn, bp[ql * 4 + 2]);
    p3 = relu2(p3, dn, bp[ql * 4 + 3]);
    {
        int slot = (ql + row) & 15;              // rotate to spread LDS banks
        uint32_t* dst = &ht[(row * 16 + slot) * 4];
        dst[0] = pack2(p0.x, p0.y);
        dst[1] = pack2(p1.x, p1.y);
        dst[2] = pack2(p2.x, p2.y);
        dst[3] = pack2(p3.x, p3.y);
    }
    __syncthreads();
    // ---- transform phase: wave w handles nt = 2w, 2w+1 ----
    int quad = lane >> 4;
    int m = lane & 15;
    int wid = tid >> 6;
    bf16x8 A[4];
#pragma unroll
    for (int c = 0; c < 4; c++) {
        int sl = (c * 4 + quad + m) & 15;
        A[c] = *(const bf16x8*)&ht[(m * 16 + sl) * 4];
    }
    int strip = blockIdx.x;
#pragma unroll
    for (int u = 0; u < 2; u++) {
        int nt = wid * 2 + u;
        f32x4 a = {0.f, 0.f, 0.f, 0.f};
        a = __builtin_amdgcn_mfma_f32_16x16x32_bf16(A[0], Wfrag[(0 * 8 + nt) * 64 + lane], a, 0, 0, 0);
        a = __builtin_amdgcn_mfma_f32_16x16x32_bf16(A[1], Wfrag[(1 * 8 + nt) * 64 + lane], a, 0, 0, 0);
        a = __builtin_amdgcn_mfma_f32_16x16x32_bf16(A[2], Wfrag[(2 * 8 + nt) * 64 + lane], a, 0, 0, 0);
        a = __builtin_amdgcn_mfma_f32_16x16x32_bf16(A[3], Wfrag[(3 * 8 + nt) * 64 + lane], a, 0, 0, 0);
#pragma unroll
        for (int r = 0; r < 4; r++) {
            float v = a[r];
            float nb = __shfl_xor(v, 1);
            int s16 = __builtin_amdgcn_cvt_pk_fp8_f32(v, nb, 0, false);
            int hi  = __shfl_xor(s16, 2);
            if (!(lane & 3)) {
                int orow = strip * 16 + quad * 4 + r;
                int oc = (nt * 16 + m) >> 2;
                tout[(size_t)orow * 32 + oc] = (uint32_t)(s16 & 0xffff) | ((uint32_t)hi << 16);
            }
        }
    }
}

// ---- last layer: aggregation + fused pool (4 nodes/wave) ----
__global__ __launch_bounds__(256) void k_agg_pool(
        const uint32_t* __restrict__ t, const int* __restrict__ offs,
        const int* __restrict__ cnt, const int2* __restrict__ csr,
        const float* __restrict__ dinv, const float* __restrict__ bias,
        const float* __restrict__ lw, const int* __restrict__ batch,
        float* __restrict__ pp) {
    int tid = threadIdx.x;
    int lane = tid & 63;
    int ql = lane & 15;
    int grp = lane & 48;
    int g4 = grp << 2, lq8 = ql << 3;
    int node = blockIdx.x * 16 + (tid >> 6) * 4 + (lane >> 4);
    int beg = offs[node];
    int num = cnt[node] + 1;
    float dn = dinv[node];
    f32x2 p0 = {0.f, 0.f}, p1 = {0.f, 0.f}, p2 = {0.f, 0.f}, p3 = {0.f, 0.f};
    aggregate_node((const char*)t, csr, beg, num, ql, g4, lq8, p0, p1, p2, p3);
    const f32x2* bp = (const f32x2*)bias;
    p0 = relu2(p0, dn, bp[ql * 4 + 0]);
    p1 = relu2(p1, dn, bp[ql * 4 + 1]);
    p2 = relu2(p2, dn, bp[ql * 4 + 2]);
    p3 = relu2(p3, dn, bp[ql * 4 + 3]);
    const f32x2* wp2 = (const f32x2*)lw;
    f32x2 q0 = wp2[ql * 4 + 0], q1 = wp2[ql * 4 + 1];
    f32x2 q2 = wp2[ql * 4 + 2], q3 = wp2[ql * 4 + 3];
    float d = p0.x * q0.x + p0.y * q0.y + p1.x * q1.x + p1.y * q1.y
            + p2.x * q2.x + p2.y * q2.y + p3.x * q3.x + p3.y * q3.y;
    for (int off = 8; off; off >>= 1) d += __shfl_down(d, off);
    if (ql == 0)
        atomicAdd(&pp[(blockIdx.x & (PSLOTS - 1)) * G_GRAPHS + batch[node]], d);
}

// ---- final: out[g] = (sum over slots)/cnt_g + lb ----
__global__ void k_final(const float* __restrict__ pp, const int* __restrict__ batch,
                        const float* __restrict__ lb, float* __restrict__ out) {
    int g = threadIdx.x;   // 64 threads
    float s = 0.f;
#pragma unroll
    for (int k = 0; k < PSLOTS; k++) s += pp[k * G_GRAPHS + g];
    int lo = 0, hi = N_NODES;
    while (lo < hi) { int m = (lo + hi) >> 1; if (batch[m] < g) lo = m + 1; else hi = m; }
    int beg = lo;
    hi = N_NODES;
    while (lo < hi) { int m = (lo + hi) >> 1; if (batch[m] < g + 1) lo = m + 1; else hi = m; }
    float c = fmaxf((float)(lo - beg), 1.0f);
    out[g] = s / c + lb[0];
}

extern "C" void kernel_launch(void* const* d_in, const int* in_sizes, int n_in,
                              void* d_out, int out_size, void* d_ws, size_t ws_size,
                              hipStream_t stream) {
    const float* x   = (const float*)d_in[0];
    const float* ew  = (const float*)d_in[1];
    const int*   ei  = (const int*)d_in[2];
    const int*   bat = (const int*)d_in[3];
    const float* W1  = (const float*)d_in[4];
    const float* b1  = (const float*)d_in[5];
    const float* W2  = (const float*)d_in[6];
    const float* b2  = (const float*)d_in[7];
    const float* W3  = (const float*)d_in[8];
    const float* b3  = (const float*)d_in[9];
    const float* lw  = (const float*)d_in[10];
    const float* lb  = (const float*)d_in[11];
    float* out = (float*)d_out;

    char* w = (char*)d_ws;
    size_t o = 0;
    auto carve = [&](size_t bytes) -> void* {
        void* p = w + o;
        o = (o + bytes + 255) & ~(size_t)255;
        return p;
    };
    float*    pp     = (float*)carve((size_t)PSLOTS * G_GRAPHS * 4);
    int*      parts  = (int*)  carve((size_t)NBK * NDB * 4);
    int*      bbase  = (int*)  carve((size_t)NBK * NDB * 4);
    int*      totals = (int*)  carve((size_t)NBK * 4);
    uint2*    recs   = (uint2*)carve((size_t)N_EDGES * 8);
    int*      cnt    = (int*)  carve((size_t)N_NODES * 4);
    float*    dinv   = (float*)carve((size_t)N_NODES * 4);
    int*      offs   = (int*)  carve((size_t)N_NODES * 4);
    int2*     csr    = (int2*) carve((size_t)NTOT * 8);
    uint32_t* tA     = (uint32_t*)carve((size_t)N_NODES * 128);   // fp8 rows
    uint32_t* tB     = (uint32_t*)carve((size_t)N_NODES * 128);   // fp8 rows
    uint16_t* wsz    = (uint16_t*)carve((size_t)3 * 16384 * 2);   // frag-order W1,W2,W3
    (void)ws_size; (void)in_sizes; (void)n_in; (void)out_size;

    // k_wswz also zeroes pp (first 16 blocks) — no separate memset dispatch
    k_wswz<<<192, 256, 0, stream>>>(W1, W2, W3, wsz, pp);
    // fused: layer-1 transform (MFMA, global W-frags) + LDS bucket histogram
    k_tr_count<<<NTB + NDB, 256, 0, stream>>>(ei, x, (const bf16x8*)wsz, tA, parts);
    k_bscan<<<NBK, 256, 0, stream>>>(parts, bbase, totals);
    // bucket starts computed inline in k_scatter/k_build (k_starts folded away)
    k_scatter<<<NDB, 256, 0, stream>>>(ei, ew, bbase, totals, recs);
    k_build<<<NBK, 256, 0, stream>>>(recs, totals, cnt, dinv, offs, csr);
    k_norm<<<(NTOT + 255) / 256, 256, 0, stream>>>(csr, dinv);

    // fused aggregate+transform per layer boundary (h never leaves LDS)
    k_agg_tr<<<NSTRIPS, 256, 0, stream>>>(tA, offs, cnt, csr, dinv, b1,
                                          (const bf16x8*)(wsz + 16384), tB);
    k_agg_tr<<<NSTRIPS, 256, 0, stream>>>(tB, offs, cnt, csr, dinv, b2,
                                          (const bf16x8*)(wsz + 2 * 16384), tA);
    k_agg_pool<<<NSTRIPS, 256, 0, stream>>>(tA, offs, cnt, csr, dinv, b3, lw, bat, pp);

    k_final<<<1, G_GRAPHS, 0, stream>>>(pp, bat, lb, out);
}